// Round 9
// baseline (1825.664 us; speedup 1.0000x reference)
//
#include <hip/hip_runtime.h>
#include <hip/hip_bf16.h>

#define NUM_NODES 50000
#define DIM 64
#define NUM_EDGES 800000
#define NUM_GRAPHS 3
#define TOT_NODES (NUM_NODES * NUM_GRAPHS)      // 150000
#define EPS 1e-12f

#define NB2 391                                  // buckets per graph: dst>>7 (50000/128)
#define TB2 (NB2 * NUM_GRAPHS)                   // 1173
#define PCAP2 2816                               // padded bucket capacity (mean 2048, +17 sigma)
#define P3_CHUNK 8192
#define P3_BLOCKS ((NUM_EDGES + P3_CHUNK - 1) / P3_CHUNK)   // 98
#define TSTRIDE 68                               // LDS tile row stride (f32) — bank spread

typedef unsigned short ushort_t;
typedef unsigned int uint_t;
typedef unsigned int uint4v __attribute__((ext_vector_type(4)));       // 16 B

__device__ __forceinline__ ushort_t f2bf(float f) {
    uint_t x = __float_as_uint(f);
    uint_t r = (x + 0x7FFFu + ((x >> 16) & 1u)) >> 16;   // RNE
    return (ushort_t)r;
}

// ---------------- L2 normalize input -> bf16 shared table ----------------
__global__ void l2norm_kernel(const float* __restrict__ in, ushort_t* __restrict__ out) {
    int row = blockIdx.x * (blockDim.x >> 6) + (threadIdx.x >> 6);
    int lane = threadIdx.x & 63;
    if (row >= NUM_NODES) return;
    float v = in[(long)row * DIM + lane];
    float s = v * v;
    #pragma unroll
    for (int off = 32; off > 0; off >>= 1)
        s += __shfl_xor(s, off, 64);
    float inv = 1.0f / fmaxf(sqrtf(s), EPS);
    out[(long)row * DIM + lane] = f2bf(v * inv);
}

// ---------------- partition edges into padded 128-node buckets (LDS-staged) ----------------
__global__ __launch_bounds__(512) void partition_kernel(
        const int* __restrict__ e0, const int* __restrict__ e1, const int* __restrict__ e2,
        int* __restrict__ gcnt, uint_t* __restrict__ part) {
    __shared__ uint_t recs[P3_CHUNK];        // 32 KB
    __shared__ int h[NB2], lstart[NB2], gbase[NB2], lcur[NB2];   // 6.3 KB
    __shared__ int sc[512];                  // 2 KB

    int g = blockIdx.y;
    const int* ei = (g == 0) ? e0 : (g == 1) ? e1 : e2;
    const int* srcp = ei;
    const int* dstp = ei + NUM_EDGES;
    int base = blockIdx.x * P3_CHUNK;
    int n = min(P3_CHUNK, NUM_EDGES - base);
    int t = threadIdx.x;

    for (int i = t; i < NB2; i += 512) h[i] = 0;
    __syncthreads();
    for (int i = t; i < n; i += 512)
        atomicAdd(&h[dstp[base + i] >> 7], 1);
    __syncthreads();

    // block scan over NB2 (<=512) with 512 threads
    {
        int v = (t < NB2) ? h[t] : 0;
        sc[t] = v;
        __syncthreads();
        #pragma unroll
        for (int off = 1; off < 512; off <<= 1) {
            int add = (t >= off) ? sc[t - off] : 0;
            __syncthreads();
            sc[t] += add;
            __syncthreads();
        }
        if (t < NB2) {
            int ex = sc[t] - v;
            lstart[t] = ex;
            lcur[t] = ex;
            gbase[t] = (v > 0) ? atomicAdd(&gcnt[g * NB2 + t], v) : 0;
        }
    }
    __syncthreads();

    // place records into LDS, bucket-grouped
    for (int i = t; i < n; i += 512) {
        int s = srcp[base + i];
        int d = dstp[base + i];
        int pos = atomicAdd(&lcur[d >> 7], 1);
        recs[pos] = ((uint_t)d << 16) | (uint_t)s;
    }
    __syncthreads();

    // stream out: consecutive LDS slots -> consecutive global slots per bucket segment
    for (int i = t; i < n; i += 512) {
        uint_t r = recs[i];
        int b = r >> 23;                      // dst>>7
        int off = gbase[b] + (i - lstart[b]);
        if (off < PCAP2)                      // capacity clamp (p ~ 0)
            part[(long)(g * NB2 + b) * PCAP2 + off] = r;
    }
}

// ---------------- degrees -> dinv (per 128-node bucket) ----------------
__global__ void degree_kernel(const uint_t* __restrict__ part, const int* __restrict__ gcnt,
                              float* __restrict__ dinv) {
    __shared__ int h[128];
    int b = blockIdx.x;                       // 0..TB2-1
    int g = b / NB2;
    int bhi = b - g * NB2;
    int t = threadIdx.x;                      // 256 threads
    if (t < 128) h[t] = 0;
    __syncthreads();
    int n = min(gcnt[b], PCAP2);
    long s0 = (long)b * PCAP2;
    for (int i = t; i < n; i += 256)
        atomicAdd(&h[(part[s0 + i] >> 16) & 127], 1);
    __syncthreads();
    if (t < 128) {
        int node = (bhi << 7) + t;
        if (node < NUM_NODES)
            dinv[g * NUM_NODES + node] = (h[t] > 0) ? rsqrtf((float)h[t]) : 0.0f;
    }
}

// ---------------- layer 1 scatter: tile[t] += dinv_s * xn[s]; write dinv_t^2 * tile ----------------
__global__ __launch_bounds__(512) void conv1s_kernel(
        const ushort_t* __restrict__ xn, const uint_t* __restrict__ part,
        const int* __restrict__ gcnt, const float* __restrict__ dinv,
        ushort_t* __restrict__ bufA) {
    __shared__ float tile[128 * TSTRIDE];     // 34.8 KB
    int b = blockIdx.x;                       // graph-major: b = g*NB2 + bhi
    int g = b / NB2;
    int bhi = b - g * NB2;
    int t = threadIdx.x;

    for (int i = t; i < 128 * TSTRIDE; i += 512) tile[i] = 0.0f;
    __syncthreads();

    int n = min(gcnt[b], PCAP2);
    long s0 = (long)b * PCAP2;
    const float* dv = dinv + g * NUM_NODES;
    int grp = t >> 3, li = t & 7;             // 64 groups x 8 lanes

    int i = grp;
    for (; i + 64 < n; i += 128) {
        uint_t r0 = part[s0 + i];
        uint_t r1 = part[s0 + i + 64];
        int sA = r0 & 0xFFFFu, sB = r1 & 0xFFFFu;
        float dA = dv[sA], dB = dv[sB];
        uint4v wA = *(const uint4v*)(xn + (long)sA * DIM + li * 8);
        uint4v wB = *(const uint4v*)(xn + (long)sB * DIM + li * 8);
        float* tA = tile + ((r0 >> 16) & 127) * TSTRIDE + li * 8;
        float* tB = tile + ((r1 >> 16) & 127) * TSTRIDE + li * 8;
        atomicAdd(&tA[0], dA * __uint_as_float(wA[0] << 16));
        atomicAdd(&tA[1], dA * __uint_as_float(wA[0] & 0xFFFF0000u));
        atomicAdd(&tA[2], dA * __uint_as_float(wA[1] << 16));
        atomicAdd(&tA[3], dA * __uint_as_float(wA[1] & 0xFFFF0000u));
        atomicAdd(&tA[4], dA * __uint_as_float(wA[2] << 16));
        atomicAdd(&tA[5], dA * __uint_as_float(wA[2] & 0xFFFF0000u));
        atomicAdd(&tA[6], dA * __uint_as_float(wA[3] << 16));
        atomicAdd(&tA[7], dA * __uint_as_float(wA[3] & 0xFFFF0000u));
        atomicAdd(&tB[0], dB * __uint_as_float(wB[0] << 16));
        atomicAdd(&tB[1], dB * __uint_as_float(wB[0] & 0xFFFF0000u));
        atomicAdd(&tB[2], dB * __uint_as_float(wB[1] << 16));
        atomicAdd(&tB[3], dB * __uint_as_float(wB[1] & 0xFFFF0000u));
        atomicAdd(&tB[4], dB * __uint_as_float(wB[2] << 16));
        atomicAdd(&tB[5], dB * __uint_as_float(wB[2] & 0xFFFF0000u));
        atomicAdd(&tB[6], dB * __uint_as_float(wB[3] << 16));
        atomicAdd(&tB[7], dB * __uint_as_float(wB[3] & 0xFFFF0000u));
    }
    for (; i < n; i += 64) {
        uint_t r = part[s0 + i];
        int s = r & 0xFFFFu;
        float d = dv[s];
        uint4v w = *(const uint4v*)(xn + (long)s * DIM + li * 8);
        float* tr = tile + ((r >> 16) & 127) * TSTRIDE + li * 8;
        atomicAdd(&tr[0], d * __uint_as_float(w[0] << 16));
        atomicAdd(&tr[1], d * __uint_as_float(w[0] & 0xFFFF0000u));
        atomicAdd(&tr[2], d * __uint_as_float(w[1] << 16));
        atomicAdd(&tr[3], d * __uint_as_float(w[1] & 0xFFFF0000u));
        atomicAdd(&tr[4], d * __uint_as_float(w[2] << 16));
        atomicAdd(&tr[5], d * __uint_as_float(w[2] & 0xFFFF0000u));
        atomicAdd(&tr[6], d * __uint_as_float(w[3] << 16));
        atomicAdd(&tr[7], d * __uint_as_float(w[3] & 0xFFFF0000u));
    }
    __syncthreads();

    // writeout: 8 waves, 2 rows per wave-iter (32 lanes/row, 2 dims/lane)
    int wv = t >> 6, ln = t & 63;
    #pragma unroll
    for (int rr = 0; rr < 8; ++rr) {
        int r = wv * 16 + rr * 2 + (ln >> 5);
        int node = (bhi << 7) + r;
        if (node < NUM_NODES) {
            int c = (ln & 31) * 2;
            float v0 = tile[r * TSTRIDE + c];
            float v1 = tile[r * TSTRIDE + c + 1];
            float dt = dv[node];
            float scl = dt * dt;
            uint_t o = (uint_t)f2bf(v0 * scl) | ((uint_t)f2bf(v1 * scl) << 16);
            ((uint_t*)(bufA + ((long)(g * NUM_NODES + node)) * DIM))[ln & 31] = o;
        }
    }
}

// ---------------- layer 2 scatter + row L2-norm + weight -> ybuf ----------------
__global__ __launch_bounds__(512) void conv2s_kernel(
        const ushort_t* __restrict__ bufA, const uint_t* __restrict__ part,
        const int* __restrict__ gcnt, const float* __restrict__ alpha,
        ushort_t* __restrict__ ybuf) {
    __shared__ float tile[128 * TSTRIDE];     // 34.8 KB
    int b = blockIdx.x;                       // graph-major
    int g = b / NB2;
    int bhi = b - g * NB2;
    int t = threadIdx.x;

    for (int i = t; i < 128 * TSTRIDE; i += 512) tile[i] = 0.0f;
    __syncthreads();

    int n = min(gcnt[b], PCAP2);
    long s0 = (long)b * PCAP2;
    const ushort_t* tbl = bufA + (long)g * NUM_NODES * DIM;
    int grp = t >> 3, li = t & 7;

    int i = grp;
    for (; i + 64 < n; i += 128) {
        uint_t r0 = part[s0 + i];
        uint_t r1 = part[s0 + i + 64];
        int sA = r0 & 0xFFFFu, sB = r1 & 0xFFFFu;
        uint4v wA = *(const uint4v*)(tbl + (long)sA * DIM + li * 8);
        uint4v wB = *(const uint4v*)(tbl + (long)sB * DIM + li * 8);
        float* tA = tile + ((r0 >> 16) & 127) * TSTRIDE + li * 8;
        float* tB = tile + ((r1 >> 16) & 127) * TSTRIDE + li * 8;
        atomicAdd(&tA[0], __uint_as_float(wA[0] << 16));
        atomicAdd(&tA[1], __uint_as_float(wA[0] & 0xFFFF0000u));
        atomicAdd(&tA[2], __uint_as_float(wA[1] << 16));
        atomicAdd(&tA[3], __uint_as_float(wA[1] & 0xFFFF0000u));
        atomicAdd(&tA[4], __uint_as_float(wA[2] << 16));
        atomicAdd(&tA[5], __uint_as_float(wA[2] & 0xFFFF0000u));
        atomicAdd(&tA[6], __uint_as_float(wA[3] << 16));
        atomicAdd(&tA[7], __uint_as_float(wA[3] & 0xFFFF0000u));
        atomicAdd(&tB[0], __uint_as_float(wB[0] << 16));
        atomicAdd(&tB[1], __uint_as_float(wB[0] & 0xFFFF0000u));
        atomicAdd(&tB[2], __uint_as_float(wB[1] << 16));
        atomicAdd(&tB[3], __uint_as_float(wB[1] & 0xFFFF0000u));
        atomicAdd(&tB[4], __uint_as_float(wB[2] << 16));
        atomicAdd(&tB[5], __uint_as_float(wB[2] & 0xFFFF0000u));
        atomicAdd(&tB[6], __uint_as_float(wB[3] << 16));
        atomicAdd(&tB[7], __uint_as_float(wB[3] & 0xFFFF0000u));
    }
    for (; i < n; i += 64) {
        uint_t r = part[s0 + i];
        int s = r & 0xFFFFu;
        uint4v w = *(const uint4v*)(tbl + (long)s * DIM + li * 8);
        float* tr = tile + ((r >> 16) & 127) * TSTRIDE + li * 8;
        atomicAdd(&tr[0], __uint_as_float(w[0] << 16));
        atomicAdd(&tr[1], __uint_as_float(w[0] & 0xFFFF0000u));
        atomicAdd(&tr[2], __uint_as_float(w[1] << 16));
        atomicAdd(&tr[3], __uint_as_float(w[1] & 0xFFFF0000u));
        atomicAdd(&tr[4], __uint_as_float(w[2] << 16));
        atomicAdd(&tr[5], __uint_as_float(w[2] & 0xFFFF0000u));
        atomicAdd(&tr[6], __uint_as_float(w[3] << 16));
        atomicAdd(&tr[7], __uint_as_float(w[3] & 0xFFFF0000u));
    }
    __syncthreads();

    // softmax(alpha) -> clip -> renormalize, pick w[g]
    float al0 = alpha[0], al1 = alpha[1], al2 = alpha[2];
    float m = fmaxf(al0, fmaxf(al1, al2));
    float e0 = expf(al0 - m), e1 = expf(al1 - m), e2 = expf(al2 - m);
    float es = e0 + e1 + e2;
    float w0 = fmaxf(e0 / es, 1e-4f);
    float w1 = fmaxf(e1 / es, 1e-4f);
    float w2 = fmaxf(e2 / es, 1e-4f);
    float wsum = w0 + w1 + w2;
    float wg = ((g == 0) ? w0 : (g == 1) ? w1 : w2) / wsum;

    // writeout: per row L2-norm (dinv_t row-scale cancels), weight, bf16
    int wv = t >> 6, ln = t & 63;
    #pragma unroll
    for (int rr = 0; rr < 8; ++rr) {
        int r = wv * 16 + rr * 2 + (ln >> 5);
        int node = (bhi << 7) + r;
        if (node < NUM_NODES) {
            int c = (ln & 31) * 2;
            float v0 = tile[r * TSTRIDE + c];
            float v1 = tile[r * TSTRIDE + c + 1];
            float ss = v0 * v0 + v1 * v1;
            #pragma unroll
            for (int off = 1; off < 32; off <<= 1)
                ss += __shfl_xor(ss, off, 64);     // off<32: stays within the 32-lane half
            float scl = wg / fmaxf(sqrtf(ss), EPS);
            uint_t o = (uint_t)f2bf(v0 * scl) | ((uint_t)f2bf(v1 * scl) << 16);
            ((uint_t*)(ybuf + ((long)(g * NUM_NODES + node)) * DIM))[ln & 31] = o;
        }
    }
}

// ---------------- blend: out = y0 + y1 + y2 (streamed) ----------------
__global__ void blend_kernel(const ushort_t* __restrict__ ybuf, float* __restrict__ out) {
    int i = blockIdx.x * blockDim.x + threadIdx.x;   // 8-dim chunk id
    if (i >= NUM_NODES * DIM / 8) return;
    uint4v w0 = *(const uint4v*)(ybuf + (long)i * 8);
    uint4v w1 = *(const uint4v*)(ybuf + (long)NUM_NODES * DIM + (long)i * 8);
    uint4v w2 = *(const uint4v*)(ybuf + 2L * NUM_NODES * DIM + (long)i * 8);
    float r[8];
    #pragma unroll
    for (int j = 0; j < 8; ++j) r[j] = 0.0f;
    #pragma unroll
    for (int j = 0; j < 4; ++j) {
        r[2*j]   += __uint_as_float(w0[j] << 16) + __uint_as_float(w1[j] << 16) + __uint_as_float(w2[j] << 16);
        r[2*j+1] += __uint_as_float(w0[j] & 0xFFFF0000u) + __uint_as_float(w1[j] & 0xFFFF0000u) + __uint_as_float(w2[j] & 0xFFFF0000u);
    }
    float* p = out + (long)i * 8;
    *(float4*)p = make_float4(r[0], r[1], r[2], r[3]);
    *(float4*)(p + 4) = make_float4(r[4], r[5], r[6], r[7]);
}

extern "C" void kernel_launch(void* const* d_in, const int* in_sizes, int n_in,
                              void* d_out, int out_size, void* d_ws, size_t ws_size,
                              hipStream_t stream) {
    const float* x     = (const float*)d_in[0];
    const float* alpha = (const float*)d_in[1];
    const int* e0 = (const int*)d_in[2];
    const int* e1 = (const int*)d_in[3];
    const int* e2 = (const int*)d_in[4];
    float* out = (float*)d_out;

    // workspace layout (~59 MB)
    ushort_t* xn   = (ushort_t*)d_ws;                          // 3,200,000 bf16  (6.4 MB)
    ushort_t* bufA = xn + (long)NUM_NODES * DIM;               // 9,600,000 bf16  (19.2 MB)
    ushort_t* ybuf = bufA + (long)TOT_NODES * DIM;             // 9,600,000 bf16  (19.2 MB)
    float* dinv    = (float*)(ybuf + (long)TOT_NODES * DIM);   // 150,000 f32
    int* gcnt      = (int*)(dinv + TOT_NODES);                 // 1,176 ints
    uint_t* part   = (uint_t*)(gcnt + 1176);                   // 1173*2816 u32   (13.2 MB)

    const int wave_grid = (NUM_NODES * 64 + 255) / 256;        // l2norm: 1 wave/row

    // normalize input once (f32 -> bf16 shared table)
    l2norm_kernel<<<wave_grid, 256, 0, stream>>>(x, xn);

    // ---- partition into padded 128-node buckets ----
    hipMemsetAsync(gcnt, 0, TB2 * sizeof(int), stream);
    {
        dim3 grd(P3_BLOCKS, NUM_GRAPHS);
        partition_kernel<<<grd, 512, 0, stream>>>(e0, e1, e2, gcnt, part);
    }
    // ---- degrees -> dinv ----
    degree_kernel<<<TB2, 256, 0, stream>>>(part, gcnt, dinv);

    // ---- layer 1 (scatter into LDS tiles; graph-major block order) ----
    conv1s_kernel<<<TB2, 512, 0, stream>>>(xn, part, gcnt, dinv, bufA);
    // ---- layer 2 + norm + weight (scatter into LDS tiles) ----
    conv2s_kernel<<<TB2, 512, 0, stream>>>(bufA, part, gcnt, alpha, ybuf);
    // ---- blend ----
    {
        int n8 = NUM_NODES * DIM / 8;
        blend_kernel<<<(n8 + 255) / 256, 256, 0, stream>>>(ybuf, out);
    }
}

// Round 10
// 260.507 us; speedup vs baseline: 7.0081x; 7.0081x over previous
//
#include <hip/hip_runtime.h>
#include <hip/hip_bf16.h>

#define NUM_NODES 50000
#define DIM 64
#define NUM_EDGES 800000
#define NUM_GRAPHS 3
#define TOT_NODES (NUM_NODES * NUM_GRAPHS)      // 150000
#define EPS 1e-12f

#define NB2 391                                  // buckets per graph: dst>>7
#define TB2 (NB2 * NUM_GRAPHS)                   // 1173
#define PCAP2 2816                               // padded capacity (mean 2048, +17 sigma)
#define P3_CHUNK 4096
#define P3_BLOCKS ((NUM_EDGES + P3_CHUNK - 1) / P3_CHUNK)   // 196

typedef unsigned short ushort_t;
typedef unsigned int uint_t;
typedef unsigned int uint4v __attribute__((ext_vector_type(4)));       // 16 B
typedef unsigned short ushort8v __attribute__((ext_vector_type(8)));   // 16 B

__device__ __forceinline__ ushort_t f2bf(float f) {
    uint_t x = __float_as_uint(f);
    uint_t r = (x + 0x7FFFu + ((x >> 16) & 1u)) >> 16;   // RNE
    return (ushort_t)r;
}

// unpack 8 bf16 (as uint4) accumulate
__device__ __forceinline__ void unpack_fma(uint4v w, float d, float* a) {
    a[0] += d * __uint_as_float(w[0] << 16);
    a[1] += d * __uint_as_float(w[0] & 0xFFFF0000u);
    a[2] += d * __uint_as_float(w[1] << 16);
    a[3] += d * __uint_as_float(w[1] & 0xFFFF0000u);
    a[4] += d * __uint_as_float(w[2] << 16);
    a[5] += d * __uint_as_float(w[2] & 0xFFFF0000u);
    a[6] += d * __uint_as_float(w[3] << 16);
    a[7] += d * __uint_as_float(w[3] & 0xFFFF0000u);
}
__device__ __forceinline__ void unpack_add(uint4v w, float* a) {
    a[0] += __uint_as_float(w[0] << 16);
    a[1] += __uint_as_float(w[0] & 0xFFFF0000u);
    a[2] += __uint_as_float(w[1] << 16);
    a[3] += __uint_as_float(w[1] & 0xFFFF0000u);
    a[4] += __uint_as_float(w[2] << 16);
    a[5] += __uint_as_float(w[2] & 0xFFFF0000u);
    a[6] += __uint_as_float(w[3] << 16);
    a[7] += __uint_as_float(w[3] & 0xFFFF0000u);
}

// ---------------- L2 normalize input -> bf16 shared table ----------------
__global__ void l2norm_kernel(const float* __restrict__ in, ushort_t* __restrict__ out) {
    int row = blockIdx.x * (blockDim.x >> 6) + (threadIdx.x >> 6);
    int lane = threadIdx.x & 63;
    if (row >= NUM_NODES) return;
    float v = in[(long)row * DIM + lane];
    float s = v * v;
    #pragma unroll
    for (int off = 32; off > 0; off >>= 1)
        s += __shfl_xor(s, off, 64);
    float inv = 1.0f / fmaxf(sqrtf(s), EPS);
    out[(long)row * DIM + lane] = f2bf(v * inv);
}

// ---------------- partition edges into padded 128-node buckets (LDS-staged) ----------------
__global__ __launch_bounds__(512) void partition_kernel(
        const int* __restrict__ e0, const int* __restrict__ e1, const int* __restrict__ e2,
        int* __restrict__ gcnt, uint_t* __restrict__ part) {
    __shared__ uint_t recs[P3_CHUNK];        // 16 KB
    __shared__ int h[NB2], lstart[NB2], gbase[NB2], lcur[NB2];   // 6.3 KB
    __shared__ int sc[512];                  // 2 KB

    int g = blockIdx.y;
    const int* ei = (g == 0) ? e0 : (g == 1) ? e1 : e2;
    const int* srcp = ei;
    const int* dstp = ei + NUM_EDGES;
    int base = blockIdx.x * P3_CHUNK;
    int n = min(P3_CHUNK, NUM_EDGES - base);
    int t = threadIdx.x;

    for (int i = t; i < NB2; i += 512) h[i] = 0;
    __syncthreads();
    for (int i = t; i < n; i += 512)
        atomicAdd(&h[dstp[base + i] >> 7], 1);
    __syncthreads();

    // block scan over NB2 (<=512)
    {
        int v = (t < NB2) ? h[t] : 0;
        sc[t] = v;
        __syncthreads();
        #pragma unroll
        for (int off = 1; off < 512; off <<= 1) {
            int add = (t >= off) ? sc[t - off] : 0;
            __syncthreads();
            sc[t] += add;
            __syncthreads();
        }
        if (t < NB2) {
            int ex = sc[t] - v;
            lstart[t] = ex;
            lcur[t] = ex;
            gbase[t] = (v > 0) ? atomicAdd(&gcnt[g * NB2 + t], v) : 0;
        }
    }
    __syncthreads();

    // place records into LDS, bucket-grouped
    for (int i = t; i < n; i += 512) {
        int s = srcp[base + i];
        int d = dstp[base + i];
        int pos = atomicAdd(&lcur[d >> 7], 1);
        recs[pos] = ((uint_t)d << 16) | (uint_t)s;
    }
    __syncthreads();

    // stream out: consecutive LDS slots -> consecutive global slots per bucket segment
    for (int i = t; i < n; i += 512) {
        uint_t r = recs[i];
        int b = r >> 23;                      // dst>>7
        int off = gbase[b] + (i - lstart[b]);
        if (off < PCAP2)                      // capacity clamp (p ~ 0)
            part[(long)(g * NB2 + b) * PCAP2 + off] = r;
    }
}

// ---------------- per-bucket fine sort -> esort (in place) + row_start/row_end + dinv ----------------
// esort is written into the FIRST HALF of this bucket's own part region (read-before-write safe)
__global__ __launch_bounds__(512) void bucket_sort_kernel(
        uint_t* __restrict__ part, const int* __restrict__ gcnt,
        int* __restrict__ row_start, int* __restrict__ row_end, float* __restrict__ dinv) {
    __shared__ uint_t recs[PCAP2];           // 11.3 KB
    __shared__ int hist[128], lcur[128], sc[128];

    int b = blockIdx.x;                       // 0..TB2-1
    int g = b / NB2;
    int bhi = b - g * NB2;
    long s0 = (long)b * PCAP2;
    int n = min(gcnt[b], PCAP2);
    int t = threadIdx.x;

    if (t < 128) hist[t] = 0;
    __syncthreads();
    for (int i = t; i < n; i += 512) {
        uint_t r = part[s0 + i];
        recs[i] = r;
        atomicAdd(&hist[(r >> 16) & 127], 1);
    }
    __syncthreads();
    int v = 0;
    if (t < 128) { v = hist[t]; sc[t] = v; }
    __syncthreads();
    #pragma unroll
    for (int off = 1; off < 128; off <<= 1) {
        int add = 0;
        if (t < 128 && t >= off) add = sc[t - off];
        __syncthreads();
        if (t < 128) sc[t] += add;
        __syncthreads();
    }
    if (t < 128) {
        int ex = sc[t] - v;
        lcur[t] = ex;
        int node = (bhi << 7) + t;
        if (node < NUM_NODES) {
            int k = g * NUM_NODES + node;
            int base = (int)(2 * s0);         // ushort index into (ushort*)part
            row_start[k] = base + ex;
            row_end[k]   = base + ex + v;
            dinv[k] = (v > 0) ? rsqrtf((float)v) : 0.0f;
        }
    }
    __syncthreads();

    ushort_t* es = (ushort_t*)part;
    for (int i = t; i < n; i += 512) {
        uint_t r = recs[i];
        int dl = (r >> 16) & 127;
        int pos = atomicAdd(&lcur[dl], 1);
        es[2 * s0 + pos] = (ushort_t)(r & 0xFFFFu);
    }
}

// ---------------- layer 1, grid (row, g): b[t] = dinv_t^2 * sum dinv_s * xn[s] ----------------
__global__ void conv1_all_kernel(const ushort_t* __restrict__ xn,
                                 const ushort_t* __restrict__ esort,
                                 const int* __restrict__ row_start,
                                 const int* __restrict__ row_end,
                                 const float* __restrict__ dinv,
                                 ushort_t* __restrict__ bufA) {
    int row = blockIdx.x * (blockDim.x >> 6) + (threadIdx.x >> 6);
    int g = blockIdx.y;
    int lane = threadIdx.x & 63;
    int sub = lane >> 3;          // 0..7: which edge of the group
    int li  = lane & 7;           // 0..7: dims [li*8, li*8+8)
    if (row >= NUM_NODES) return;

    int k = g * NUM_NODES + row;
    int start = __builtin_amdgcn_readfirstlane(row_start[k]);
    int end   = __builtin_amdgcn_readfirstlane(row_end[k]);
    const float* dv = dinv + g * NUM_NODES;

    float a[8];
    #pragma unroll
    for (int j = 0; j < 8; ++j) a[j] = 0.0f;

    int i = start;
    for (; i + 32 <= end; i += 32) {
        int s0 = esort[i + sub];
        int s1 = esort[i + 8 + sub];
        int s2 = esort[i + 16 + sub];
        int s3 = esort[i + 24 + sub];
        float d0 = dv[s0], d1 = dv[s1], d2 = dv[s2], d3 = dv[s3];
        uint4v w0 = *(const uint4v*)(xn + (long)s0 * DIM + li * 8);
        uint4v w1 = *(const uint4v*)(xn + (long)s1 * DIM + li * 8);
        uint4v w2 = *(const uint4v*)(xn + (long)s2 * DIM + li * 8);
        uint4v w3 = *(const uint4v*)(xn + (long)s3 * DIM + li * 8);
        unpack_fma(w0, d0, a);
        unpack_fma(w1, d1, a);
        unpack_fma(w2, d2, a);
        unpack_fma(w3, d3, a);
    }
    for (; i + 16 <= end; i += 16) {
        int s0 = esort[i + sub];
        int s1 = esort[i + 8 + sub];
        float d0 = dv[s0], d1 = dv[s1];
        uint4v w0 = *(const uint4v*)(xn + (long)s0 * DIM + li * 8);
        uint4v w1 = *(const uint4v*)(xn + (long)s1 * DIM + li * 8);
        unpack_fma(w0, d0, a);
        unpack_fma(w1, d1, a);
    }
    for (; i < end; i += 8) {
        int e = i + sub;
        if (e < end) {
            int s = esort[e];
            float d = dv[s];
            uint4v w = *(const uint4v*)(xn + (long)s * DIM + li * 8);
            unpack_fma(w, d, a);
        }
    }
    #pragma unroll
    for (int off = 8; off < 64; off <<= 1) {
        #pragma unroll
        for (int j = 0; j < 8; ++j)
            a[j] += __shfl_xor(a[j], off, 64);
    }
    float dt = dv[row];
    float scl = dt * dt;
    if (sub == 0) {
        ushort8v o;
        #pragma unroll
        for (int j = 0; j < 8; ++j) o[j] = f2bf(a[j] * scl);
        *(ushort8v*)(bufA + (long)k * DIM + li * 8) = o;
    }
}

// ---------------- layer 2, grid (row, g): y_g = w_g * acc/||acc|| -> ybuf ----------------
__global__ void conv2_kernel(const ushort_t* __restrict__ bufA,
                             const ushort_t* __restrict__ esort,
                             const int* __restrict__ row_start,
                             const int* __restrict__ row_end,
                             const float* __restrict__ alpha,
                             ushort_t* __restrict__ ybuf) {
    int row = blockIdx.x * (blockDim.x >> 6) + (threadIdx.x >> 6);
    int g = blockIdx.y;
    int lane = threadIdx.x & 63;
    int sub = lane >> 3;
    int li  = lane & 7;
    if (row >= NUM_NODES) return;

    // softmax(alpha) -> clip -> renormalize, pick w[g]
    float al0 = alpha[0], al1 = alpha[1], al2 = alpha[2];
    float m = fmaxf(al0, fmaxf(al1, al2));
    float e0 = expf(al0 - m), e1 = expf(al1 - m), e2 = expf(al2 - m);
    float es = e0 + e1 + e2;
    float w0 = fmaxf(e0 / es, 1e-4f);
    float w1 = fmaxf(e1 / es, 1e-4f);
    float w2 = fmaxf(e2 / es, 1e-4f);
    float wsum = w0 + w1 + w2;
    float wg = ((g == 0) ? w0 : (g == 1) ? w1 : w2) / wsum;

    int k = g * NUM_NODES + row;
    int start = __builtin_amdgcn_readfirstlane(row_start[k]);
    int end   = __builtin_amdgcn_readfirstlane(row_end[k]);
    const ushort_t* tbl = bufA + (long)g * NUM_NODES * DIM;

    float a[8];
    #pragma unroll
    for (int j = 0; j < 8; ++j) a[j] = 0.0f;

    int i = start;
    for (; i + 32 <= end; i += 32) {
        int s0 = esort[i + sub];
        int s1 = esort[i + 8 + sub];
        int s2 = esort[i + 16 + sub];
        int s3 = esort[i + 24 + sub];
        uint4v v0 = *(const uint4v*)(tbl + (long)s0 * DIM + li * 8);
        uint4v v1 = *(const uint4v*)(tbl + (long)s1 * DIM + li * 8);
        uint4v v2 = *(const uint4v*)(tbl + (long)s2 * DIM + li * 8);
        uint4v v3 = *(const uint4v*)(tbl + (long)s3 * DIM + li * 8);
        unpack_add(v0, a);
        unpack_add(v1, a);
        unpack_add(v2, a);
        unpack_add(v3, a);
    }
    for (; i + 16 <= end; i += 16) {
        int s0 = esort[i + sub];
        int s1 = esort[i + 8 + sub];
        uint4v v0 = *(const uint4v*)(tbl + (long)s0 * DIM + li * 8);
        uint4v v1 = *(const uint4v*)(tbl + (long)s1 * DIM + li * 8);
        unpack_add(v0, a);
        unpack_add(v1, a);
    }
    for (; i < end; i += 8) {
        int e = i + sub;
        if (e < end) {
            int s = esort[e];
            uint4v w = *(const uint4v*)(tbl + (long)s * DIM + li * 8);
            unpack_add(w, a);
        }
    }
    #pragma unroll
    for (int off = 8; off < 64; off <<= 1) {
        #pragma unroll
        for (int j = 0; j < 8; ++j)
            a[j] += __shfl_xor(a[j], off, 64);
    }
    // row L2 norm (dinv_t row-scale cancels)
    float s = 0.0f;
    #pragma unroll
    for (int j = 0; j < 8; ++j) s += a[j] * a[j];
    #pragma unroll
    for (int off = 1; off < 8; off <<= 1)
        s += __shfl_xor(s, off, 64);
    float scl = wg / fmaxf(sqrtf(s), EPS);

    if (sub == 0) {
        ushort8v o;
        #pragma unroll
        for (int j = 0; j < 8; ++j) o[j] = f2bf(a[j] * scl);
        *(ushort8v*)(ybuf + (long)k * DIM + li * 8) = o;
    }
}

// ---------------- blend: out = y0 + y1 + y2 (streamed) ----------------
__global__ void blend_kernel(const ushort_t* __restrict__ ybuf, float* __restrict__ out) {
    int i = blockIdx.x * blockDim.x + threadIdx.x;   // 8-dim chunk id
    if (i >= NUM_NODES * DIM / 8) return;
    uint4v w0 = *(const uint4v*)(ybuf + (long)i * 8);
    uint4v w1 = *(const uint4v*)(ybuf + (long)NUM_NODES * DIM + (long)i * 8);
    uint4v w2 = *(const uint4v*)(ybuf + 2L * NUM_NODES * DIM + (long)i * 8);
    float r[8];
    #pragma unroll
    for (int j = 0; j < 8; ++j) r[j] = 0.0f;
    unpack_add(w0, r);
    unpack_add(w1, r);
    unpack_add(w2, r);
    float* p = out + (long)i * 8;
    *(float4*)p = make_float4(r[0], r[1], r[2], r[3]);
    *(float4*)(p + 4) = make_float4(r[4], r[5], r[6], r[7]);
}

extern "C" void kernel_launch(void* const* d_in, const int* in_sizes, int n_in,
                              void* d_out, int out_size, void* d_ws, size_t ws_size,
                              hipStream_t stream) {
    const float* x     = (const float*)d_in[0];
    const float* alpha = (const float*)d_in[1];
    const int* e0 = (const int*)d_in[2];
    const int* e1 = (const int*)d_in[3];
    const int* e2 = (const int*)d_in[4];
    float* out = (float*)d_out;

    // workspace layout (~60 MB)
    ushort_t* xn   = (ushort_t*)d_ws;                          // 3,200,000 bf16  (6.4 MB)
    ushort_t* bufA = xn + (long)NUM_NODES * DIM;               // 9,600,000 bf16  (19.2 MB)
    ushort_t* ybuf = bufA + (long)TOT_NODES * DIM;             // 9,600,000 bf16  (19.2 MB)
    float* dinv    = (float*)(ybuf + (long)TOT_NODES * DIM);   // 150,000 f32
    int* row_start = (int*)(dinv + TOT_NODES);                 // 150,016
    int* row_end   = row_start + 150016;                       // 150,016
    int* gcnt      = row_end + 150016;                         // 1,176
    uint_t* part   = (uint_t*)(gcnt + 1176);                   // 1173*2816 u32   (13.2 MB)
    // esort lives IN-PLACE in part (first half of each bucket's region) after bucket_sort

    const int wave_grid = (NUM_NODES * 64 + 255) / 256;        // 1 wave/row, 4 waves/block

    // normalize input once (f32 -> bf16 shared table)
    l2norm_kernel<<<wave_grid, 256, 0, stream>>>(x, xn);

    // ---- partition into padded 128-node buckets ----
    hipMemsetAsync(gcnt, 0, TB2 * sizeof(int), stream);
    {
        dim3 grd(P3_BLOCKS, NUM_GRAPHS);
        partition_kernel<<<grd, 512, 0, stream>>>(e0, e1, e2, gcnt, part);
    }
    // ---- per-bucket fine sort (esort in place) + row offsets + dinv ----
    bucket_sort_kernel<<<TB2, 512, 0, stream>>>(part, gcnt, row_start, row_end, dinv);

    const ushort_t* esort = (const ushort_t*)part;

    // ---- layer 1 (graph-major 2D grid) ----
    {
        dim3 grd(wave_grid, NUM_GRAPHS);
        conv1_all_kernel<<<grd, 256, 0, stream>>>(xn, esort, row_start, row_end, dinv, bufA);
    }
    // ---- layer 2 (graph-major 2D grid) -> ybuf ----
    {
        dim3 grd(wave_grid, NUM_GRAPHS);
        conv2_kernel<<<grd, 256, 0, stream>>>(bufA, esort, row_start, row_end, alpha, ybuf);
    }
    // ---- blend ----
    {
        int n8 = NUM_NODES * DIM / 8;
        blend_kernel<<<(n8 + 255) / 256, 256, 0, stream>>>(ybuf, out);
    }
}

// Round 11
// 237.147 us; speedup vs baseline: 7.6984x; 1.0985x over previous
//
#include <hip/hip_runtime.h>
#include <hip/hip_bf16.h>

#define NUM_NODES 50000
#define DIM 64
#define NUM_EDGES 800000
#define NUM_GRAPHS 3
#define TOT_NODES (NUM_NODES * NUM_GRAPHS)      // 150000
#define EPS 1e-12f

#define NB2 391                                  // buckets per graph: dst>>7
#define TB2 (NB2 * NUM_GRAPHS)                   // 1173
#define PCAP2 2816                               // padded capacity (mean 2048, +17 sigma)
#define P3_CHUNK 4096
#define P3_BLOCKS ((NUM_EDGES + P3_CHUNK - 1) / P3_CHUNK)   // 196

typedef unsigned short ushort_t;
typedef unsigned int uint_t;
typedef unsigned int uint4v __attribute__((ext_vector_type(4)));       // 16 B
typedef unsigned short ushort8v __attribute__((ext_vector_type(8)));   // 16 B
typedef float f32x8 __attribute__((ext_vector_type(8)));

__device__ __forceinline__ ushort_t f2bf(float f) {
    uint_t x = __float_as_uint(f);
    uint_t r = (x + 0x7FFFu + ((x >> 16) & 1u)) >> 16;   // RNE
    return (ushort_t)r;
}

// unpack 8 bf16 (as uint4) into f32x8 — 1 VALU/elem; downstream vector math -> v_pk_*
__device__ __forceinline__ f32x8 unpack8(uint4v w) {
    f32x8 r;
    r[0] = __uint_as_float(w[0] << 16);
    r[1] = __uint_as_float(w[0] & 0xFFFF0000u);
    r[2] = __uint_as_float(w[1] << 16);
    r[3] = __uint_as_float(w[1] & 0xFFFF0000u);
    r[4] = __uint_as_float(w[2] << 16);
    r[5] = __uint_as_float(w[2] & 0xFFFF0000u);
    r[6] = __uint_as_float(w[3] << 16);
    r[7] = __uint_as_float(w[3] & 0xFFFF0000u);
    return r;
}

// ---------------- L2 normalize input -> bf16 shared table ----------------
__global__ void l2norm_kernel(const float* __restrict__ in, ushort_t* __restrict__ out) {
    int row = blockIdx.x * (blockDim.x >> 6) + (threadIdx.x >> 6);
    int lane = threadIdx.x & 63;
    if (row >= NUM_NODES) return;
    float v = in[(long)row * DIM + lane];
    float s = v * v;
    #pragma unroll
    for (int off = 32; off > 0; off >>= 1)
        s += __shfl_xor(s, off, 64);
    float inv = 1.0f / fmaxf(sqrtf(s), EPS);
    out[(long)row * DIM + lane] = f2bf(v * inv);
}

// ---------------- partition edges into padded 128-node buckets (LDS-staged) ----------------
__global__ __launch_bounds__(512) void partition_kernel(
        const int* __restrict__ e0, const int* __restrict__ e1, const int* __restrict__ e2,
        int* __restrict__ gcnt, uint_t* __restrict__ part) {
    __shared__ uint_t recs[P3_CHUNK];        // 16 KB
    __shared__ int h[NB2], lstart[NB2], gbase[NB2], lcur[NB2];   // 6.3 KB
    __shared__ int wsum[8];

    int g = blockIdx.y;
    const int* ei = (g == 0) ? e0 : (g == 1) ? e1 : e2;
    const int* srcp = ei;
    const int* dstp = ei + NUM_EDGES;
    int base = blockIdx.x * P3_CHUNK;
    int n = min(P3_CHUNK, NUM_EDGES - base);
    int t = threadIdx.x;
    int wid = t >> 6, ln = t & 63;

    for (int i = t; i < NB2; i += 512) h[i] = 0;
    __syncthreads();
    for (int i = t; i < n; i += 512)
        atomicAdd(&h[dstp[base + i] >> 7], 1);
    __syncthreads();

    // wave-shfl exclusive scan over NB2 bins (8 waves, 2 barriers)
    {
        int v = (t < NB2) ? h[t] : 0;
        int s = v;
        #pragma unroll
        for (int off = 1; off < 64; off <<= 1) {
            int u = __shfl_up(s, off, 64);
            if (ln >= off) s += u;
        }
        if (ln == 63) wsum[wid] = s;
        __syncthreads();
        int prefix = 0;
        #pragma unroll
        for (int w = 0; w < 8; ++w)
            if (w < wid) prefix += wsum[w];
        if (t < NB2) {
            int ex = prefix + s - v;
            lstart[t] = ex;
            lcur[t] = ex;
            gbase[t] = (v > 0) ? atomicAdd(&gcnt[g * NB2 + t], v) : 0;
        }
    }
    __syncthreads();

    // place records into LDS, bucket-grouped
    for (int i = t; i < n; i += 512) {
        int s = srcp[base + i];
        int d = dstp[base + i];
        int pos = atomicAdd(&lcur[d >> 7], 1);
        recs[pos] = ((uint_t)d << 16) | (uint_t)s;
    }
    __syncthreads();

    // stream out: consecutive LDS slots -> consecutive global slots per bucket segment
    for (int i = t; i < n; i += 512) {
        uint_t r = recs[i];
        int b = r >> 23;                      // dst>>7
        int off = gbase[b] + (i - lstart[b]);
        if (off < PCAP2)                      // capacity clamp (p ~ 0)
            part[(long)(g * NB2 + b) * PCAP2 + off] = r;
    }
}

// ---------------- per-bucket fine sort -> esort (in place, LDS-staged) + rows + dinv ----------------
__global__ __launch_bounds__(512) void bucket_sort_kernel(
        uint_t* __restrict__ part, const int* __restrict__ gcnt,
        int* __restrict__ row_start, int* __restrict__ row_end, float* __restrict__ dinv) {
    __shared__ uint_t recs[PCAP2];           // 11.3 KB
    __shared__ ushort_t es_l[PCAP2];         // 5.6 KB
    __shared__ int hist[128], lcur[128];
    __shared__ int w0sum;

    int b = blockIdx.x;                       // 0..TB2-1
    int g = b / NB2;
    int bhi = b - g * NB2;
    long s0 = (long)b * PCAP2;
    int n = min(gcnt[b], PCAP2);
    int t = threadIdx.x;
    int ln = t & 63;

    if (t < 128) hist[t] = 0;
    __syncthreads();
    for (int i = t; i < n; i += 512) {
        uint_t r = part[s0 + i];
        recs[i] = r;
        atomicAdd(&hist[(r >> 16) & 127], 1);
    }
    __syncthreads();

    // wave-shfl exclusive scan over 128 bins (2 waves)
    int v = (t < 128) ? hist[t] : 0;
    int s = v;
    #pragma unroll
    for (int off = 1; off < 64; off <<= 1) {
        int u = __shfl_up(s, off, 64);
        if (ln >= off) s += u;
    }
    if (t == 63) w0sum = s;
    __syncthreads();
    if (t < 128) {
        int prefix = (t >= 64) ? w0sum : 0;
        int ex = prefix + s - v;
        lcur[t] = ex;
        int node = (bhi << 7) + t;
        if (node < NUM_NODES) {
            int k = g * NUM_NODES + node;
            int base = (int)(2 * s0);         // ushort index into (ushort*)part
            row_start[k] = base + ex;
            row_end[k]   = base + ex + v;
            dinv[k] = (v > 0) ? rsqrtf((float)v) : 0.0f;
        }
    }
    __syncthreads();

    // fine-sort into LDS, then coalesced copy-out over the bucket's own region
    for (int i = t; i < n; i += 512) {
        uint_t r = recs[i];
        int dl = (r >> 16) & 127;
        int pos = atomicAdd(&lcur[dl], 1);
        es_l[pos] = (ushort_t)(r & 0xFFFFu);
    }
    __syncthreads();
    uint_t* es_out = (uint_t*)((ushort_t*)part + 2 * s0);
    int nw = (n + 1) >> 1;
    const uint_t* es_lw = (const uint_t*)es_l;
    for (int i = t; i < nw; i += 512)
        es_out[i] = es_lw[i];
}

// ---------------- layer 1, grid (row, g): b[t] = dinv_t^2 * sum dinv_s * xn[s] ----------------
__global__ void conv1_all_kernel(const ushort_t* __restrict__ xn,
                                 const ushort_t* __restrict__ esort,
                                 const int* __restrict__ row_start,
                                 const int* __restrict__ row_end,
                                 const float* __restrict__ dinv,
                                 ushort_t* __restrict__ bufA) {
    int row = blockIdx.x * (blockDim.x >> 6) + (threadIdx.x >> 6);
    int g = blockIdx.y;
    int lane = threadIdx.x & 63;
    int sub = lane >> 3;          // 0..7: which edge of the group
    int li  = lane & 7;           // 0..7: dims [li*8, li*8+8)
    if (row >= NUM_NODES) return;

    int k = g * NUM_NODES + row;
    int start = __builtin_amdgcn_readfirstlane(row_start[k]);
    int end   = __builtin_amdgcn_readfirstlane(row_end[k]);
    const float* dv = dinv + g * NUM_NODES;

    f32x8 a = {0, 0, 0, 0, 0, 0, 0, 0};

    int i = start;
    for (; i + 32 <= end; i += 32) {
        int s0 = esort[i + sub];
        int s1 = esort[i + 8 + sub];
        int s2 = esort[i + 16 + sub];
        int s3 = esort[i + 24 + sub];
        float d0 = dv[s0], d1 = dv[s1], d2 = dv[s2], d3 = dv[s3];
        uint4v w0 = *(const uint4v*)(xn + (long)s0 * DIM + li * 8);
        uint4v w1 = *(const uint4v*)(xn + (long)s1 * DIM + li * 8);
        uint4v w2 = *(const uint4v*)(xn + (long)s2 * DIM + li * 8);
        uint4v w3 = *(const uint4v*)(xn + (long)s3 * DIM + li * 8);
        a += unpack8(w0) * d0;
        a += unpack8(w1) * d1;
        a += unpack8(w2) * d2;
        a += unpack8(w3) * d3;
    }
    for (; i + 16 <= end; i += 16) {
        int s0 = esort[i + sub];
        int s1 = esort[i + 8 + sub];
        float d0 = dv[s0], d1 = dv[s1];
        uint4v w0 = *(const uint4v*)(xn + (long)s0 * DIM + li * 8);
        uint4v w1 = *(const uint4v*)(xn + (long)s1 * DIM + li * 8);
        a += unpack8(w0) * d0;
        a += unpack8(w1) * d1;
    }
    for (; i < end; i += 8) {
        int e = i + sub;
        if (e < end) {
            int s = esort[e];
            float d = dv[s];
            uint4v w = *(const uint4v*)(xn + (long)s * DIM + li * 8);
            a += unpack8(w) * d;
        }
    }
    #pragma unroll
    for (int off = 8; off < 64; off <<= 1) {
        #pragma unroll
        for (int j = 0; j < 8; ++j)
            a[j] += __shfl_xor(a[j], off, 64);
    }
    float dt = dv[row];
    float scl = dt * dt;
    if (sub == 0) {
        ushort8v o;
        #pragma unroll
        for (int j = 0; j < 8; ++j) o[j] = f2bf(a[j] * scl);
        *(ushort8v*)(bufA + (long)k * DIM + li * 8) = o;
    }
}

// ---------------- layer 2 (in-wave g-loop) + l2norm + blend -> f32 out ----------------
__global__ void conv2_finalize_kernel(const ushort_t* __restrict__ bufA,
                                      const ushort_t* __restrict__ esort,
                                      const int* __restrict__ row_start,
                                      const int* __restrict__ row_end,
                                      const float* __restrict__ alpha,
                                      float* __restrict__ out) {
    int row = blockIdx.x * (blockDim.x >> 6) + (threadIdx.x >> 6);
    int lane = threadIdx.x & 63;
    int sub = lane >> 3;
    int li  = lane & 7;
    if (row >= NUM_NODES) return;

    // softmax(alpha) -> clip -> renormalize
    float al0 = alpha[0], al1 = alpha[1], al2 = alpha[2];
    float m = fmaxf(al0, fmaxf(al1, al2));
    float e0 = expf(al0 - m), e1 = expf(al1 - m), e2 = expf(al2 - m);
    float es = e0 + e1 + e2;
    float w0 = fmaxf(e0 / es, 1e-4f);
    float w1 = fmaxf(e1 / es, 1e-4f);
    float w2 = fmaxf(e2 / es, 1e-4f);
    float wsum = w0 + w1 + w2;

    f32x8 res = {0, 0, 0, 0, 0, 0, 0, 0};

    #pragma unroll
    for (int g = 0; g < NUM_GRAPHS; ++g) {
        int k = g * NUM_NODES + row;
        int start = __builtin_amdgcn_readfirstlane(row_start[k]);
        int end   = __builtin_amdgcn_readfirstlane(row_end[k]);
        const ushort_t* tbl = bufA + (long)g * NUM_NODES * DIM;

        f32x8 a = {0, 0, 0, 0, 0, 0, 0, 0};

        int i = start;
        for (; i + 32 <= end; i += 32) {
            int s0 = esort[i + sub];
            int s1 = esort[i + 8 + sub];
            int s2 = esort[i + 16 + sub];
            int s3 = esort[i + 24 + sub];
            uint4v v0 = *(const uint4v*)(tbl + (long)s0 * DIM + li * 8);
            uint4v v1 = *(const uint4v*)(tbl + (long)s1 * DIM + li * 8);
            uint4v v2 = *(const uint4v*)(tbl + (long)s2 * DIM + li * 8);
            uint4v v3 = *(const uint4v*)(tbl + (long)s3 * DIM + li * 8);
            a += unpack8(v0);
            a += unpack8(v1);
            a += unpack8(v2);
            a += unpack8(v3);
        }
        for (; i + 16 <= end; i += 16) {
            int s0 = esort[i + sub];
            int s1 = esort[i + 8 + sub];
            uint4v v0 = *(const uint4v*)(tbl + (long)s0 * DIM + li * 8);
            uint4v v1 = *(const uint4v*)(tbl + (long)s1 * DIM + li * 8);
            a += unpack8(v0);
            a += unpack8(v1);
        }
        for (; i < end; i += 8) {
            int e = i + sub;
            if (e < end) {
                int s = esort[e];
                uint4v w = *(const uint4v*)(tbl + (long)s * DIM + li * 8);
                a += unpack8(w);
            }
        }
        #pragma unroll
        for (int off = 8; off < 64; off <<= 1) {
            #pragma unroll
            for (int j = 0; j < 8; ++j)
                a[j] += __shfl_xor(a[j], off, 64);
        }
        // row L2 norm (dinv_t row-scale cancels)
        float s = 0.0f;
        #pragma unroll
        for (int j = 0; j < 8; ++j) s += a[j] * a[j];
        #pragma unroll
        for (int off = 1; off < 8; off <<= 1)
            s += __shfl_xor(s, off, 64);
        float wg = ((g == 0) ? w0 : (g == 1) ? w1 : w2) / wsum;
        float scl = wg / fmaxf(sqrtf(s), EPS);
        res += a * scl;
    }

    if (sub == 0) {
        float* p = out + (long)row * DIM + li * 8;
        *(float4*)p = make_float4(res[0], res[1], res[2], res[3]);
        *(float4*)(p + 4) = make_float4(res[4], res[5], res[6], res[7]);
    }
}

extern "C" void kernel_launch(void* const* d_in, const int* in_sizes, int n_in,
                              void* d_out, int out_size, void* d_ws, size_t ws_size,
                              hipStream_t stream) {
    const float* x     = (const float*)d_in[0];
    const float* alpha = (const float*)d_in[1];
    const int* e0 = (const int*)d_in[2];
    const int* e1 = (const int*)d_in[3];
    const int* e2 = (const int*)d_in[4];
    float* out = (float*)d_out;

    // workspace layout (~41 MB)
    ushort_t* xn   = (ushort_t*)d_ws;                          // 3,200,000 bf16  (6.4 MB)
    ushort_t* bufA = xn + (long)NUM_NODES * DIM;               // 9,600,000 bf16  (19.2 MB)
    float* dinv    = (float*)(bufA + (long)TOT_NODES * DIM);   // 150,000 f32
    int* row_start = (int*)(dinv + TOT_NODES);                 // 150,016
    int* row_end   = row_start + 150016;                       // 150,016
    int* gcnt      = row_end + 150016;                         // 1,176
    uint_t* part   = (uint_t*)(gcnt + 1176);                   // 1173*2816 u32   (13.2 MB)
    // esort lives IN-PLACE in part (first half of each bucket's region) after bucket_sort

    const int wave_grid = (NUM_NODES * 64 + 255) / 256;        // 1 wave/row, 4 waves/block

    // normalize input once (f32 -> bf16 shared table)
    l2norm_kernel<<<wave_grid, 256, 0, stream>>>(x, xn);

    // ---- partition into padded 128-node buckets ----
    hipMemsetAsync(gcnt, 0, TB2 * sizeof(int), stream);
    {
        dim3 grd(P3_BLOCKS, NUM_GRAPHS);
        partition_kernel<<<grd, 512, 0, stream>>>(e0, e1, e2, gcnt, part);
    }
    // ---- per-bucket fine sort (esort in place) + row offsets + dinv ----
    bucket_sort_kernel<<<TB2, 512, 0, stream>>>(part, gcnt, row_start, row_end, dinv);

    const ushort_t* esort = (const ushort_t*)part;

    // ---- layer 1 (graph-major 2D grid) ----
    {
        dim3 grd(wave_grid, NUM_GRAPHS);
        conv1_all_kernel<<<grd, 256, 0, stream>>>(xn, esort, row_start, row_end, dinv, bufA);
    }
    // ---- layer 2 + normalize + blend -> f32 out ----
    conv2_finalize_kernel<<<wave_grid, 256, 0, stream>>>(bufA, esort, row_start, row_end, alpha, out);
}

// Round 12
// 209.250 us; speedup vs baseline: 8.7248x; 1.1333x over previous
//
#include <hip/hip_runtime.h>
#include <hip/hip_bf16.h>

#define NUM_NODES 50000
#define DIM 64
#define NUM_EDGES 800000
#define NUM_GRAPHS 3
#define TOT_NODES (NUM_NODES * NUM_GRAPHS)      // 150000
#define EPS 1e-12f

#define NB2 391                                  // buckets per graph: dst>>7
#define TB2 (NB2 * NUM_GRAPHS)                   // 1173
#define PCAP2 2816                               // padded capacity (mean 2048, +17 sigma)
#define P3_CHUNK 4096
#define P3_BLOCKS ((NUM_EDGES + P3_CHUNK - 1) / P3_CHUNK)   // 196

typedef unsigned short ushort_t;
typedef unsigned int uint_t;
typedef unsigned int uint4v __attribute__((ext_vector_type(4)));       // 16 B
typedef unsigned short ushort8v __attribute__((ext_vector_type(8)));   // 16 B
typedef float f32x8 __attribute__((ext_vector_type(8)));

__device__ __forceinline__ ushort_t f2bf(float f) {
    uint_t x = __float_as_uint(f);
    uint_t r = (x + 0x7FFFu + ((x >> 16) & 1u)) >> 16;   // RNE
    return (ushort_t)r;
}

// unpack 8 bf16 (as uint4) into f32x8 — 1 VALU/elem; vector math -> v_pk_*
__device__ __forceinline__ f32x8 unpack8(uint4v w) {
    f32x8 r;
    r[0] = __uint_as_float(w[0] << 16);
    r[1] = __uint_as_float(w[0] & 0xFFFF0000u);
    r[2] = __uint_as_float(w[1] << 16);
    r[3] = __uint_as_float(w[1] & 0xFFFF0000u);
    r[4] = __uint_as_float(w[2] << 16);
    r[5] = __uint_as_float(w[2] & 0xFFFF0000u);
    r[6] = __uint_as_float(w[3] << 16);
    r[7] = __uint_as_float(w[3] & 0xFFFF0000u);
    return r;
}

// ---------------- partition edges into padded 128-node buckets (LDS-staged) ----------------
__global__ __launch_bounds__(512) void partition_kernel(
        const int* __restrict__ e0, const int* __restrict__ e1, const int* __restrict__ e2,
        int* __restrict__ gcnt, uint_t* __restrict__ part) {
    __shared__ uint_t recs[P3_CHUNK];        // 16 KB
    __shared__ int h[NB2], lstart[NB2], gbase[NB2], lcur[NB2];   // 6.3 KB
    __shared__ int wsum[8];

    int g = blockIdx.y;
    const int* ei = (g == 0) ? e0 : (g == 1) ? e1 : e2;
    const int* srcp = ei;
    const int* dstp = ei + NUM_EDGES;
    int base = blockIdx.x * P3_CHUNK;
    int n = min(P3_CHUNK, NUM_EDGES - base);
    int t = threadIdx.x;
    int wid = t >> 6, ln = t & 63;

    for (int i = t; i < NB2; i += 512) h[i] = 0;
    __syncthreads();
    for (int i = t; i < n; i += 512)
        atomicAdd(&h[dstp[base + i] >> 7], 1);
    __syncthreads();

    // wave-shfl exclusive scan over NB2 bins
    {
        int v = (t < NB2) ? h[t] : 0;
        int s = v;
        #pragma unroll
        for (int off = 1; off < 64; off <<= 1) {
            int u = __shfl_up(s, off, 64);
            if (ln >= off) s += u;
        }
        if (ln == 63) wsum[wid] = s;
        __syncthreads();
        int prefix = 0;
        #pragma unroll
        for (int w = 0; w < 8; ++w)
            if (w < wid) prefix += wsum[w];
        if (t < NB2) {
            int ex = prefix + s - v;
            lstart[t] = ex;
            lcur[t] = ex;
            gbase[t] = (v > 0) ? atomicAdd(&gcnt[g * NB2 + t], v) : 0;
        }
    }
    __syncthreads();

    // place records into LDS, bucket-grouped
    for (int i = t; i < n; i += 512) {
        int s = srcp[base + i];
        int d = dstp[base + i];
        int pos = atomicAdd(&lcur[d >> 7], 1);
        recs[pos] = ((uint_t)d << 16) | (uint_t)s;
    }
    __syncthreads();

    // stream out per bucket segment
    for (int i = t; i < n; i += 512) {
        uint_t r = recs[i];
        int b = r >> 23;                      // dst>>7
        int off = gbase[b] + (i - lstart[b]);
        if (off < PCAP2)
            part[(long)(g * NB2 + b) * PCAP2 + off] = r;
    }
}

// ---------------- per-bucket fine sort -> esort (in place, LDS-staged) + rows + dinv ----------------
__global__ __launch_bounds__(512) void bucket_sort_kernel(
        uint_t* __restrict__ part, const int* __restrict__ gcnt,
        int* __restrict__ row_start, int* __restrict__ row_end, float* __restrict__ dinv) {
    __shared__ uint_t recs[PCAP2];           // 11.3 KB
    __shared__ ushort_t es_l[PCAP2];         // 5.6 KB
    __shared__ int hist[128], lcur[128];
    __shared__ int w0sum;

    int b = blockIdx.x;                       // 0..TB2-1
    int g = b / NB2;
    int bhi = b - g * NB2;
    long s0 = (long)b * PCAP2;
    int n = min(gcnt[b], PCAP2);
    int t = threadIdx.x;
    int ln = t & 63;

    if (t < 128) hist[t] = 0;
    __syncthreads();
    for (int i = t; i < n; i += 512) {
        uint_t r = part[s0 + i];
        recs[i] = r;
        atomicAdd(&hist[(r >> 16) & 127], 1);
    }
    __syncthreads();

    // wave-shfl exclusive scan over 128 bins
    int v = (t < 128) ? hist[t] : 0;
    int s = v;
    #pragma unroll
    for (int off = 1; off < 64; off <<= 1) {
        int u = __shfl_up(s, off, 64);
        if (ln >= off) s += u;
    }
    if (t == 63) w0sum = s;
    __syncthreads();
    if (t < 128) {
        int prefix = (t >= 64) ? w0sum : 0;
        int ex = prefix + s - v;
        lcur[t] = ex;
        int node = (bhi << 7) + t;
        if (node < NUM_NODES) {
            int k = g * NUM_NODES + node;
            int base = (int)(2 * s0);         // ushort index into (ushort*)part
            row_start[k] = base + ex;
            row_end[k]   = base + ex + v;
            dinv[k] = (v > 0) ? rsqrtf((float)v) : 0.0f;
        }
    }
    __syncthreads();

    // fine-sort into LDS, coalesced copy-out
    for (int i = t; i < n; i += 512) {
        uint_t r = recs[i];
        int dl = (r >> 16) & 127;
        int pos = atomicAdd(&lcur[dl], 1);
        es_l[pos] = (ushort_t)(r & 0xFFFFu);
    }
    __syncthreads();
    uint_t* es_out = (uint_t*)((ushort_t*)part + 2 * s0);
    int nw = (n + 1) >> 1;
    const uint_t* es_lw = (const uint_t*)es_l;
    for (int i = t; i < nw; i += 512)
        es_out[i] = es_lw[i];
}

// ---------------- fused: l2-normalize x, premultiply by dinv_g -> 3 bf16 tables ----------------
__global__ void l2norm_premult_kernel(const float* __restrict__ x,
                                      const float* __restrict__ dinv,
                                      ushort_t* __restrict__ bufX) {
    int row = blockIdx.x * (blockDim.x >> 6) + (threadIdx.x >> 6);
    int lane = threadIdx.x & 63;
    if (row >= NUM_NODES) return;
    float v = x[(long)row * DIM + lane];
    float s = v * v;
    #pragma unroll
    for (int off = 32; off > 0; off >>= 1)
        s += __shfl_xor(s, off, 64);
    float nv = v / fmaxf(sqrtf(s), EPS);
    #pragma unroll
    for (int g = 0; g < NUM_GRAPHS; ++g) {
        float d = dinv[g * NUM_NODES + row];
        bufX[(long)(g * NUM_NODES + row) * DIM + lane] = f2bf(nv * d);
    }
}

// ---------------- layer 1, 2 rows/wave, grid (pair, g): bufA[t] = dt^2 * sum bufX_g[s] ----------------
__global__ void conv1_kernel(const ushort_t* __restrict__ bufX,
                             const ushort_t* __restrict__ esort,
                             const int* __restrict__ row_start,
                             const int* __restrict__ row_end,
                             const float* __restrict__ dinv,
                             ushort_t* __restrict__ bufA) {
    int pair = blockIdx.x * (blockDim.x >> 6) + (threadIdx.x >> 6);
    int g = blockIdx.y;
    int lane = threadIdx.x & 63;
    int half = lane >> 5;         // 0: row 2p, 1: row 2p+1
    int sub  = (lane >> 3) & 3;   // edge slot within half
    int li   = lane & 7;          // dims [li*8, li*8+8)
    int row = pair * 2 + half;
    if (row >= NUM_NODES) return;

    int k = g * NUM_NODES + row;
    int start = row_start[k];
    int end   = row_end[k];
    const ushort_t* tbl = bufX + (long)g * NUM_NODES * DIM;

    f32x8 a = {0, 0, 0, 0, 0, 0, 0, 0};
    int i = start + sub;
    for (; i + 4 < end; i += 8) {
        int s0 = esort[i];
        int s1 = esort[i + 4];
        uint4v w0 = *(const uint4v*)(tbl + (long)s0 * DIM + li * 8);
        uint4v w1 = *(const uint4v*)(tbl + (long)s1 * DIM + li * 8);
        a += unpack8(w0);
        a += unpack8(w1);
    }
    if (i < end) {
        int s = esort[i];
        uint4v w = *(const uint4v*)(tbl + (long)s * DIM + li * 8);
        a += unpack8(w);
    }
    // combine 4 subs within each 32-lane half (both rows in the same instructions)
    #pragma unroll
    for (int off = 8; off < 32; off <<= 1) {
        #pragma unroll
        for (int j = 0; j < 8; ++j)
            a[j] += __shfl_xor(a[j], off, 64);
    }
    float dt = dinv[k];
    float scl = dt * dt;
    if (sub == 0) {
        ushort8v o;
        #pragma unroll
        for (int j = 0; j < 8; ++j) o[j] = f2bf(a[j] * scl);
        *(ushort8v*)(bufA + (long)k * DIM + li * 8) = o;
    }
}

// ---------------- layer 2, 2 rows/wave, in-wave g-loop + l2norm + blend -> f32 out ----------------
__global__ void conv2_finalize_kernel(const ushort_t* __restrict__ bufA,
                                      const ushort_t* __restrict__ esort,
                                      const int* __restrict__ row_start,
                                      const int* __restrict__ row_end,
                                      const float* __restrict__ alpha,
                                      float* __restrict__ out) {
    int pair = blockIdx.x * (blockDim.x >> 6) + (threadIdx.x >> 6);
    int lane = threadIdx.x & 63;
    int half = lane >> 5;
    int sub  = (lane >> 3) & 3;
    int li   = lane & 7;
    int row = pair * 2 + half;
    if (row >= NUM_NODES) return;

    // softmax(alpha) -> clip -> renormalize
    float al0 = alpha[0], al1 = alpha[1], al2 = alpha[2];
    float m = fmaxf(al0, fmaxf(al1, al2));
    float e0 = expf(al0 - m), e1 = expf(al1 - m), e2 = expf(al2 - m);
    float es = e0 + e1 + e2;
    float w0 = fmaxf(e0 / es, 1e-4f);
    float w1 = fmaxf(e1 / es, 1e-4f);
    float w2 = fmaxf(e2 / es, 1e-4f);
    float wsum = w0 + w1 + w2;

    f32x8 res = {0, 0, 0, 0, 0, 0, 0, 0};

    #pragma unroll
    for (int g = 0; g < NUM_GRAPHS; ++g) {
        int k = g * NUM_NODES + row;
        int start = row_start[k];
        int end   = row_end[k];
        const ushort_t* tbl = bufA + (long)g * NUM_NODES * DIM;

        f32x8 a = {0, 0, 0, 0, 0, 0, 0, 0};
        int i = start + sub;
        for (; i + 4 < end; i += 8) {
            int s0 = esort[i];
            int s1 = esort[i + 4];
            uint4v v0 = *(const uint4v*)(tbl + (long)s0 * DIM + li * 8);
            uint4v v1 = *(const uint4v*)(tbl + (long)s1 * DIM + li * 8);
            a += unpack8(v0);
            a += unpack8(v1);
        }
        if (i < end) {
            int s = esort[i];
            uint4v w = *(const uint4v*)(tbl + (long)s * DIM + li * 8);
            a += unpack8(w);
        }
        #pragma unroll
        for (int off = 8; off < 32; off <<= 1) {
            #pragma unroll
            for (int j = 0; j < 8; ++j)
                a[j] += __shfl_xor(a[j], off, 64);
        }
        // row L2 norm within the 8-lane group (dinv_t row-scale cancels)
        float s = 0.0f;
        #pragma unroll
        for (int j = 0; j < 8; ++j) s += a[j] * a[j];
        #pragma unroll
        for (int off = 1; off < 8; off <<= 1)
            s += __shfl_xor(s, off, 64);
        float wg = ((g == 0) ? w0 : (g == 1) ? w1 : w2) / wsum;
        float scl = wg / fmaxf(sqrtf(s), EPS);
        res += a * scl;
    }

    if (sub == 0) {
        float* p = out + (long)row * DIM + li * 8;
        *(float4*)p = make_float4(res[0], res[1], res[2], res[3]);
        *(float4*)(p + 4) = make_float4(res[4], res[5], res[6], res[7]);
    }
}

extern "C" void kernel_launch(void* const* d_in, const int* in_sizes, int n_in,
                              void* d_out, int out_size, void* d_ws, size_t ws_size,
                              hipStream_t stream) {
    const float* x     = (const float*)d_in[0];
    const float* alpha = (const float*)d_in[1];
    const int* e0 = (const int*)d_in[2];
    const int* e1 = (const int*)d_in[3];
    const int* e2 = (const int*)d_in[4];
    float* out = (float*)d_out;

    // workspace layout (~53 MB)
    ushort_t* bufX = (ushort_t*)d_ws;                          // 3*50000*64 bf16 (19.2 MB)
    ushort_t* bufA = bufX + (long)TOT_NODES * DIM;             // 3*50000*64 bf16 (19.2 MB)
    float* dinv    = (float*)(bufA + (long)TOT_NODES * DIM);   // 150,000 f32
    int* row_start = (int*)(dinv + TOT_NODES);                 // 150,016
    int* row_end   = row_start + 150016;                       // 150,016
    int* gcnt      = row_end + 150016;                         // 1,176
    uint_t* part   = (uint_t*)(gcnt + 1176);                   // 1173*2816 u32   (13.2 MB)
    // esort lives IN-PLACE in part after bucket_sort

    const int wave_grid = (NUM_NODES * 64 + 255) / 256;        // 1 row/wave kernels
    const int pair_grid = ((NUM_NODES / 2) * 64 + 255) / 256;  // 2 rows/wave kernels

    // ---- partition into padded 128-node buckets ----
    hipMemsetAsync(gcnt, 0, TB2 * sizeof(int), stream);
    {
        dim3 grd(P3_BLOCKS, NUM_GRAPHS);
        partition_kernel<<<grd, 512, 0, stream>>>(e0, e1, e2, gcnt, part);
    }
    // ---- per-bucket fine sort (esort in place) + row offsets + dinv ----
    bucket_sort_kernel<<<TB2, 512, 0, stream>>>(part, gcnt, row_start, row_end, dinv);

    const ushort_t* esort = (const ushort_t*)part;

    // ---- l2norm + premultiply (needs dinv) ----
    l2norm_premult_kernel<<<wave_grid, 256, 0, stream>>>(x, dinv, bufX);

    // ---- layer 1 (2 rows/wave, graph-major 2D grid) ----
    {
        dim3 grd(pair_grid, NUM_GRAPHS);
        conv1_kernel<<<grd, 256, 0, stream>>>(bufX, esort, row_start, row_end, dinv, bufA);
    }
    // ---- layer 2 + normalize + blend -> f32 out ----
    conv2_finalize_kernel<<<pair_grid, 256, 0, stream>>>(bufA, esort, row_start, row_end, alpha, out);
}